// Round 2
// baseline (227.306 us; speedup 1.0000x reference)
//
#include <hip/hip_runtime.h>

// DynamicDilationUnfold: B=4, C=64, H=W=128, G=4, Cg=16, K=3, stride=1, pad=1.
// Ho=Wo=128. out[b][((g*Cg+cg)*K+kh)*K+kw][ho*Wo+wo], fp32.
//
// R1: latency-bound at 28% occupancy (1024 blocks = 4/CU). Split the channel
// loop 4-ways: each thread handles 4 of the group's 16 channels -> 4096
// blocks, ~8 resident blocks/CU. Weight/index math duplicated (VALU was 12%,
// cheap). Output stores nontemporal (write-once) to keep L2 for gathers.

constexpr int B  = 4;
constexpr int C  = 64;
constexpr int H  = 128;
constexpr int W  = 128;
constexpr int G  = 4;
constexpr int Cg = C / G;            // 16
constexpr int K  = 3;
constexpr int Ho = 128;
constexpr int Wo = 128;
constexpr int HW = H * W;            // 16384
constexpr int HoWo = Ho * Wo;        // 16384
constexpr int CPT = 4;               // channels per thread
constexpr int CHUNKS = Cg / CPT;     // 4

__global__ __launch_bounds__(256) void ddu_kernel(
    const float* __restrict__ x,      // (B, C, H, W)
    const float* __restrict__ dmap,   // (B, G, H, W)
    float* __restrict__ out)          // (B, C*K*K, Ho*Wo)
{
    const int idx = blockIdx.x * 256 + threadIdx.x;   // over B*G*CHUNKS*Ho*Wo
    const int wo    = idx & (Wo - 1);
    const int ho    = (idx >> 7) & (Ho - 1);
    const int chunk = (idx >> 14) & (CHUNKS - 1);
    const int g     = (idx >> 16) & (G - 1);
    const int b     = idx >> 18;

    const float d = dmap[((b * G + g) * HoWo) + ho * Wo + wo];

    const int cgb = chunk * CPT;
    const float* __restrict__ xg = x + (size_t)(b * C + g * Cg + cgb) * HW;
    float* __restrict__ outg = out
        + (size_t)((b * G + g) * Cg + cgb) * (K * K * HoWo)
        + (size_t)(ho * Wo + wo);

#pragma unroll
    for (int kh = 0; kh < K; ++kh) {
        const float ph  = (float)(ho - 1) + (float)kh * d;
        const float h0f = floorf(ph);
        const float lh  = ph - h0f;
        const int h0 = (int)h0f;
        const int h1 = h0 + 1;
        const bool h0v = (unsigned)h0 < (unsigned)H;
        const bool h1v = (unsigned)h1 < (unsigned)H;
        const int h0c = min(max(h0, 0), H - 1);
        const int h1c = min(max(h1, 0), H - 1);

#pragma unroll
        for (int kw = 0; kw < K; ++kw) {
            const float pw  = (float)(wo - 1) + (float)kw * d;
            const float w0f = floorf(pw);
            const float lw  = pw - w0f;
            const int w0 = (int)w0f;
            const int w1 = w0 + 1;
            const bool w0v = (unsigned)w0 < (unsigned)W;
            const bool w1v = (unsigned)w1 < (unsigned)W;
            const int w0c = min(max(w0, 0), W - 1);
            const int w1c = min(max(w1, 0), W - 1);

            const float c00 = (1.f - lh) * (1.f - lw) * (float)(h0v && w0v);
            const float c01 = (1.f - lh) * lw          * (float)(h0v && w1v);
            const float c10 = lh          * (1.f - lw) * (float)(h1v && w0v);
            const float c11 = lh          * lw          * (float)(h1v && w1v);

            const int i00 = h0c * W + w0c;
            const int i01 = h0c * W + w1c;
            const int i10 = h1c * W + w0c;
            const int i11 = h1c * W + w1c;

            float* __restrict__ o = outg + (size_t)(kh * K + kw) * HoWo;

#pragma unroll
            for (int c = 0; c < CPT; ++c) {
                const float* __restrict__ xc = xg + (size_t)c * HW;
                const float v = c00 * xc[i00] + c01 * xc[i01]
                              + c10 * xc[i10] + c11 * xc[i11];
                __builtin_nontemporal_store(v, o + (size_t)c * (K * K * HoWo));
            }
        }
    }
}

extern "C" void kernel_launch(void* const* d_in, const int* in_sizes, int n_in,
                              void* d_out, int out_size, void* d_ws, size_t ws_size,
                              hipStream_t stream) {
    const float* x    = (const float*)d_in[0];
    const float* dmap = (const float*)d_in[1];
    float* out = (float*)d_out;

    const int total = B * G * CHUNKS * Ho * Wo;   // 1,048,576 threads
    const int block = 256;
    const int grid  = total / block;              // 4096 blocks
    ddu_kernel<<<grid, block, 0, stream>>>(x, dmap, out);
}

// Round 3
// 174.446 us; speedup vs baseline: 1.3030x; 1.3030x over previous
//
#include <hip/hip_runtime.h>

// DynamicDilationUnfold: B=4, C=64, H=W=128, G=4, Cg=16, K=3, stride=1, pad=1.
// out[b][((g*Cg+cg)*K+kh)*K+kw][ho*Wo+wo], fp32.
//
// R2 finding: global-gather version is TA/L1-bound (divergent per-lane rows,
// ~1 cy per distinct cache line per wave-load; occupancy/VALU/HBM all idle).
// R3: stage input tile in LDS (zero-filled halo == reference validity mask),
// gather from LDS (ds_read2-friendly (w,w+1) pairs). One block per
// (b, g, 8-ch chunk, 64x16 tile): LDS 8*22*71 dwords ~= 48.8 KB,
// 1024 thr, 2 blocks/CU -> 32 waves/CU. Grid = 512 blocks (fully resident).

constexpr int B  = 4;
constexpr int C  = 64;
constexpr int H  = 128;
constexpr int W  = 128;
constexpr int G  = 4;
constexpr int Cg = C / G;            // 16
constexpr int K  = 3;
constexpr int Ho = 128;
constexpr int Wo = 128;
constexpr int HW = H * W;            // 16384
constexpr int HoWo = Ho * Wo;        // 16384

constexpr int TILE_H = 16;
constexpr int TILE_W = 64;
constexpr int CPB    = 8;            // channels per block (chunk)
constexpr int REG_H  = TILE_H + 6;   // 22 rows  (halo: -1 .. +5, bilinear incl.)
constexpr int REG_W  = TILE_W + 6;   // 70 cols
constexpr int LDS_STRIDE = REG_W + 1;            // 71
constexpr int LDS_CH     = REG_H * LDS_STRIDE;   // 1562 dwords per channel
constexpr int REG_ELEMS  = REG_H * REG_W;        // 1540

__global__ __launch_bounds__(1024, 8) void ddu_kernel(
    const float* __restrict__ x,      // (B, C, H, W)
    const float* __restrict__ dmap,   // (B, G, H, W)
    float* __restrict__ out)          // (B, C*K*K, Ho*Wo)
{
    __shared__ float lds[CPB * LDS_CH];          // 49,984 B

    const int tid = threadIdx.x;
    const int bid = blockIdx.x;                  // over B*G*2*8*2 = 512
    const int tw    = bid & 1;                   // 64-col tile
    const int th    = (bid >> 1) & 7;            // 16-row tile
    const int chunk = (bid >> 4) & 1;
    const int g     = (bid >> 5) & 3;
    const int b     = bid >> 7;

    const int ho0 = th * TILE_H;
    const int wo0 = tw * TILE_W;
    const int cgb = chunk * CPB;

    const float* __restrict__ xg = x + (size_t)(b * C + g * Cg + cgb) * HW;

    // ---- stage (zero-filled halo) ----
    const int r_img0 = ho0 - 1;
    const int c_img0 = wo0 - 1;
#pragma unroll
    for (int it = 0; it < 13; ++it) {
        const int i = it * 1024 + tid;
        if (i < CPB * REG_ELEMS) {
            const int ch  = i / REG_ELEMS;
            const int rem = i - ch * REG_ELEMS;
            const int r   = rem / REG_W;
            const int c   = rem - r * REG_W;
            const int ir  = r_img0 + r;
            const int ic  = c_img0 + c;
            float v = 0.f;
            if ((unsigned)ir < (unsigned)H && (unsigned)ic < (unsigned)W)
                v = xg[(size_t)ch * HW + ir * W + ic];
            lds[ch * LDS_CH + r * LDS_STRIDE + c] = v;
        }
    }
    __syncthreads();

    // ---- compute ----
    const int wi = tid & (TILE_W - 1);           // 0..63
    const int hi = tid >> 6;                     // 0..15
    const int ho = ho0 + hi;
    const int wo = wo0 + wi;

    const float d = dmap[(size_t)(b * G + g) * HoWo + ho * Wo + wo];

    float* __restrict__ outb = out
        + (size_t)b * (C * K * K) * HoWo
        + (size_t)((g * Cg + cgb) * K * K) * HoWo
        + (ho * Wo + wo);

#pragma unroll
    for (int kh = 0; kh < K; ++kh) {
        // local (region-relative) position: ph_local = hi + kh*d  (>= 0)
        const float phl = (float)hi + (float)kh * d;
        const int   r0  = (int)phl;
        const float lh  = phl - (float)r0;
#pragma unroll
        for (int kw = 0; kw < K; ++kw) {
            const float pwl = (float)wi + (float)kw * d;
            const int   c0  = (int)pwl;
            const float lw  = pwl - (float)c0;

            const float c00 = (1.f - lh) * (1.f - lw);
            const float c01 = (1.f - lh) * lw;
            const float c10 = lh * (1.f - lw);
            const float c11 = lh * lw;

            const int base = r0 * LDS_STRIDE + c0;
            float* __restrict__ o = outb + (size_t)(kh * K + kw) * HoWo;

#pragma unroll 4
            for (int ch = 0; ch < CPB; ++ch) {
                const float* __restrict__ l = lds + ch * LDS_CH + base;
                const float v = c00 * l[0] + c01 * l[1]
                              + c10 * l[LDS_STRIDE] + c11 * l[LDS_STRIDE + 1];
                __builtin_nontemporal_store(v, o + (size_t)ch * (K * K * HoWo));
            }
        }
    }
}

extern "C" void kernel_launch(void* const* d_in, const int* in_sizes, int n_in,
                              void* d_out, int out_size, void* d_ws, size_t ws_size,
                              hipStream_t stream) {
    const float* x    = (const float*)d_in[0];
    const float* dmap = (const float*)d_in[1];
    float* out = (float*)d_out;

    const int grid = B * G * 2 /*chunks*/ * 8 /*th*/ * 2 /*tw*/;   // 512
    ddu_kernel<<<grid, 1024, 0, stream>>>(x, dmap, out);
}

// Round 4
// 165.480 us; speedup vs baseline: 1.3736x; 1.0542x over previous
//
#include <hip/hip_runtime.h>

// DynamicDilationUnfold: B=4, C=64, H=W=128, G=4, Cg=16, K=3, stride=1, pad=1.
// out[b][((g*Cg+cg)*K+kh)*K+kw][ho*Wo+wo], fp32.
//
// R3: LDS-staged gather fixed the TA-bound divergent-gather problem (~98->~50us).
// R4: store-path overhaul. Theory: nontemporal dword stores run well below the
// 6.5 TB/s the poison-fill achieves with normal wide stores. Changes:
//   - normal (write-back) stores, not nontemporal
//   - float2 stores via 2-wo-per-thread coarsening (512 thr, tile 64x16)
//   - CPB 8->4 so LDS = 25 KB -> 4 blocks/CU x 8 waves = 32 waves/CU,
//     grid = 1024 blocks, fully resident. Staging fetch invariant (~25 MB).

constexpr int B  = 4;
constexpr int C  = 64;
constexpr int H  = 128;
constexpr int W  = 128;
constexpr int G  = 4;
constexpr int Cg = C / G;            // 16
constexpr int K  = 3;
constexpr int KK = K * K;
constexpr int Ho = 128;
constexpr int Wo = 128;
constexpr int HW = H * W;            // 16384
constexpr int HoWo = Ho * Wo;        // 16384

constexpr int TILE_H = 16;
constexpr int TILE_W = 64;
constexpr int CPB    = 4;            // channels per block
constexpr int REG_H  = TILE_H + 6;   // 22 rows (halo -1 .. +5)
constexpr int REG_W  = TILE_W + 6;   // 70 cols
constexpr int LDS_STRIDE = REG_W + 1;            // 71
constexpr int LDS_CH     = REG_H * LDS_STRIDE;   // 1562 dwords per channel
constexpr int REG_ELEMS  = REG_H * REG_W;        // 1540
constexpr int NTHREADS   = 512;

__global__ __launch_bounds__(NTHREADS, 8) void ddu_kernel(
    const float* __restrict__ x,      // (B, C, H, W)
    const float* __restrict__ dmap,   // (B, G, H, W)
    float* __restrict__ out)          // (B, C*K*K, Ho*Wo)
{
    __shared__ float lds[CPB * LDS_CH];          // 24,992 B

    const int tid = threadIdx.x;
    const int bid = blockIdx.x;                  // over B*G*4*8*2 = 1024
    const int tw    = bid & 1;                   // 64-col tile
    const int th    = (bid >> 1) & 7;            // 16-row tile
    const int chunk = (bid >> 4) & 3;            // 4-channel chunk
    const int g     = (bid >> 6) & 3;
    const int b     = bid >> 8;

    const int ho0 = th * TILE_H;
    const int wo0 = tw * TILE_W;
    const int cgb = chunk * CPB;

    const float* __restrict__ xg = x + (size_t)(b * C + g * Cg + cgb) * HW;

    // ---- stage (zero-filled halo == reference validity mask) ----
    const int r_img0 = ho0 - 1;
    const int c_img0 = wo0 - 1;
#pragma unroll
    for (int it = 0; it < 13; ++it) {
        const int i = it * NTHREADS + tid;
        if (i < CPB * REG_ELEMS) {
            const int ch  = i / REG_ELEMS;
            const int rem = i - ch * REG_ELEMS;
            const int r   = rem / REG_W;
            const int c   = rem - r * REG_W;
            const int ir  = r_img0 + r;
            const int ic  = c_img0 + c;
            float v = 0.f;
            if ((unsigned)ir < (unsigned)H && (unsigned)ic < (unsigned)W)
                v = xg[(size_t)ch * HW + ir * W + ic];
            lds[ch * LDS_CH + r * LDS_STRIDE + c] = v;
        }
    }
    __syncthreads();

    // ---- compute: each thread owns 2 adjacent wo ----
    const int wi2 = tid & 31;                    // wo-pair index 0..31
    const int hi  = tid >> 5;                    // 0..15
    const int ho  = ho0 + hi;
    const int wo  = wo0 + wi2 * 2;

    const float2 dv = *(const float2*)&dmap[(size_t)(b * G + g) * HoWo + ho * Wo + wo];
    const float d0 = dv.x;
    const float d1 = dv.y;

    float* __restrict__ outb = out
        + (size_t)((b * G + g) * Cg + cgb) * (KK * HoWo)
        + (size_t)(ho * Wo + wo);

    const int colbase0 = wi2 * 2;                // local col of subpixel 0
    const int colbase1 = wi2 * 2 + 1;

#pragma unroll
    for (int kh = 0; kh < K; ++kh) {
        const float phl0 = (float)hi + (float)kh * d0;
        const float phl1 = (float)hi + (float)kh * d1;
        const int   r00  = (int)phl0;
        const int   r01  = (int)phl1;
        const float lh0  = phl0 - (float)r00;
        const float lh1  = phl1 - (float)r01;

#pragma unroll
        for (int kw = 0; kw < K; ++kw) {
            const float pwl0 = (float)colbase0 + (float)kw * d0;
            const float pwl1 = (float)colbase1 + (float)kw * d1;
            const int   c00i = (int)pwl0;
            const int   c01i = (int)pwl1;
            const float lw0  = pwl0 - (float)c00i;
            const float lw1  = pwl1 - (float)c01i;

            const float a00 = (1.f - lh0) * (1.f - lw0);
            const float a01 = (1.f - lh0) * lw0;
            const float a10 = lh0 * (1.f - lw0);
            const float a11 = lh0 * lw0;

            const float b00 = (1.f - lh1) * (1.f - lw1);
            const float b01 = (1.f - lh1) * lw1;
            const float b10 = lh1 * (1.f - lw1);
            const float b11 = lh1 * lw1;

            const int base0 = r00 * LDS_STRIDE + c00i;
            const int base1 = r01 * LDS_STRIDE + c01i;

            float* __restrict__ o = outb + (size_t)(kh * K + kw) * HoWo;

#pragma unroll
            for (int ch = 0; ch < CPB; ++ch) {
                const float* __restrict__ l = lds + ch * LDS_CH;
                const float* __restrict__ l0 = l + base0;
                const float* __restrict__ l1 = l + base1;
                float2 v;
                v.x = a00 * l0[0] + a01 * l0[1]
                    + a10 * l0[LDS_STRIDE] + a11 * l0[LDS_STRIDE + 1];
                v.y = b00 * l1[0] + b01 * l1[1]
                    + b10 * l1[LDS_STRIDE] + b11 * l1[LDS_STRIDE + 1];
                *(float2*)(o + (size_t)ch * (KK * HoWo)) = v;
            }
        }
    }
}

extern "C" void kernel_launch(void* const* d_in, const int* in_sizes, int n_in,
                              void* d_out, int out_size, void* d_ws, size_t ws_size,
                              hipStream_t stream) {
    const float* x    = (const float*)d_in[0];
    const float* dmap = (const float*)d_in[1];
    float* out = (float*)d_out;

    const int grid = B * G * 4 /*chunks*/ * 8 /*th*/ * 2 /*tw*/;   // 1024
    ddu_kernel<<<grid, NTHREADS, 0, stream>>>(x, dmap, out);
}